// Round 7
// baseline (641.059 us; speedup 1.0000x reference)
//
#include <hip/hip_runtime.h>

#define DN  256   // DAGs
#define NN  1024  // nodes per DAG
#define PP  8     // max predecessors
#define LL  104   // feature dim
#define CLS 500   // classes
#define BT  512   // threads per block (8 waves -> W frags fit unified RF)
#define TMAX 64   // node tile per level pass
#define KP  232   // padded K stride in bf16 elems (116 dwords % 32 = 20 -> 2-way max, free)
#define NG  26    // float4 feature groups (104/4)

typedef __attribute__((ext_vector_type(8))) short short8;
typedef __attribute__((ext_vector_type(4))) short short4v;
typedef __attribute__((ext_vector_type(4))) float f32x4;

#define MFMA(a, b, c) __builtin_amdgcn_mfma_f32_16x16x32_bf16((a), (b), (c), 0, 0, 0)

__device__ __forceinline__ void split_bf16(float x, unsigned short& h, unsigned short& l) {
    unsigned u = __float_as_uint(x);
    h = (unsigned short)(u >> 16);
    float hf = __uint_as_float(u & 0xFFFF0000u);
    l = (unsigned short)(__float_as_uint(x - hf) >> 16);
}

// One block per DAG, 8 waves. Level-scheduled; per-level matvec batch is a
// split-bf16 MFMA GEMM with W_merge fragments pinned in registers/AGPRs.
// Cross-level software pipeline: pred indices, atom features, and all
// already-final predecessor rows for the NEXT tile are prefetched during the
// current tile's phase B, so phase A only gathers lvl==L-1 rows.
__global__ __launch_bounds__(BT, 2) void dag_level_kernel(
    const float* __restrict__ atom,      // [DN][NN][LL]
    const int*   __restrict__ pred,      // [DN][NN][PP]
    const float* __restrict__ W_single,  // [LL][LL]
    const float* __restrict__ b_single,  // [LL]
    const float* __restrict__ W_merge,   // [LL][2*LL]
    const float* __restrict__ b_merge,   // [LL]
    const float* __restrict__ attn_w,    // [LL]
    float* __restrict__ out_all,         // ws: [DN][NN][LL]
    float* __restrict__ last_buf)        // ws: [DN][LL]
{
    __shared__ __align__(16) unsigned short x_hi[TMAX][KP];  // 29.7 KB
    __shared__ __align__(16) unsigned short x_lo[TMAX][KP];  // 29.7 KB
    __shared__ int   lvl[NN];               // 4 KB
    __shared__ int   cnt[NN];               // 4 KB
    __shared__ unsigned short order[NN];    // 2 KB
    __shared__ __align__(16) float s_attn[LL];
    __shared__ float s_bm[LL];
    __shared__ int   csum[64];
    __shared__ int   s_flag, s_maxlvl;

    const int d    = blockIdx.x;
    const int tid  = threadIdx.x;
    const int wid  = tid >> 6;
    const int lane = tid & 63;
    const int p    = wid & 3;    // owned nt-pair: nt = {2p, 2p+1}

    const float* atom_d = atom + (size_t)d * NN * LL;
    const int*   pred_d = pred + (size_t)d * NN * PP;
    float*       out_d  = out_all + (size_t)d * NN * LL;

    // ---- W_merge fragments -> registers (once). B-frag layout:
    // lane holds W[col = nt*16 + (lane&15)][k = kt*32 + (lane>>4)*8 + j].
    short8 wh[2][7], wl[2][7];
    #pragma unroll
    for (int h = 0; h < 2; ++h) {
        const int r = (2*p + h)*16 + (lane & 15);
        #pragma unroll
        for (int kt = 0; kt < 7; ++kt) {
            const int k0 = kt*32 + (lane >> 4)*8;
            short8 hh, lo8;
            #pragma unroll
            for (int j = 0; j < 8; ++j) {
                float v = (r < LL && (k0 + j) < 2*LL) ? W_merge[r*2*LL + k0 + j] : 0.f;
                unsigned short a, b;
                split_bf16(v, a, b);
                hh[j] = (short)a; lo8[j] = (short)b;
            }
            wh[h][kt] = hh; wl[h][kt] = lo8;
        }
    }

    // ---- init: zero x pad cols, stage attn/bias, init flags ----
    for (int idx = tid; idx < TMAX * (KP - 2*LL); idx += BT) {
        int rr = idx / (KP - 2*LL), cc = 2*LL + (idx - rr*(KP - 2*LL));
        x_hi[rr][cc] = 0; x_lo[rr][cc] = 0;
    }
    if (tid < LL) { s_attn[tid] = attn_w[tid]; s_bm[tid] = b_merge[tid]; }
    if (tid == 0) { s_flag = 0; s_maxlvl = 0; }

    // ---- 1. level relaxation (2 nodes per thread, preds in registers) ----
    {
        int mypA[PP], mypB[PP];
        const int4* p4 = (const int4*)(pred_d + tid * PP);
        int4 a = p4[0], b = p4[1];
        mypA[0]=a.x; mypA[1]=a.y; mypA[2]=a.z; mypA[3]=a.w;
        mypA[4]=b.x; mypA[5]=b.y; mypA[6]=b.z; mypA[7]=b.w;
        const int4* q4 = (const int4*)(pred_d + (tid + BT) * PP);
        int4 c = q4[0], e = q4[1];
        mypB[0]=c.x; mypB[1]=c.y; mypB[2]=c.z; mypB[3]=c.w;
        mypB[4]=e.x; mypB[5]=e.y; mypB[6]=e.z; mypB[7]=e.w;
        lvl[tid] = 0; lvl[tid + BT] = 0;
        __syncthreads();
        for (int it = 1; it <= NN; ++it) {
            int mxA = -1, mxB = -1;
            #pragma unroll
            for (int q = 0; q < PP; ++q) {
                if (mypA[q] >= 0) mxA = max(mxA, lvl[mypA[q]]);
                if (mypB[q] >= 0) mxB = max(mxB, lvl[mypB[q]]);
            }
            bool ch = false;
            if (mxA + 1 != lvl[tid])      { lvl[tid]      = mxA + 1; ch = true; }
            if (mxB + 1 != lvl[tid + BT]) { lvl[tid + BT] = mxB + 1; ch = true; }
            if (ch) s_flag = it;
            __syncthreads();
            int f = s_flag;
            __syncthreads();
            if (f != it) break;
        }
        atomicMax(&s_maxlvl, max(lvl[tid], lvl[tid + BT]));
    }

    // ---- 2. counting sort by level ----
    cnt[tid] = 0; cnt[tid + BT] = 0;
    __syncthreads();
    atomicAdd(&cnt[lvl[tid]], 1);
    atomicAdd(&cnt[lvl[tid + BT]], 1);
    __syncthreads();
    if (tid < 64) { int s = 0; for (int i = 0; i < 16; ++i) s += cnt[tid*16 + i]; csum[tid] = s; }
    __syncthreads();
    if (tid == 0) { int run = 0; for (int t = 0; t < 64; ++t) { int c = csum[t]; csum[t] = run; run += c; } }
    __syncthreads();
    if (tid < 64) {
        int run = csum[tid];
        for (int i = 0; i < 16; ++i) { int c = cnt[tid*16 + i]; cnt[tid*16 + i] = run; run += c; }
    }
    __syncthreads();
    {
        int pos = atomicAdd(&cnt[lvl[tid]], 1);      order[pos] = (unsigned short)tid;
        pos     = atomicAdd(&cnt[lvl[tid + BT]], 1); order[pos] = (unsigned short)(tid + BT);
    }
    __syncthreads();
    // level L occupies [L==0 ? 0 : cnt[L-1], cnt[L])

    // ---- 3. level-0 (root) nodes via W_single straight from global ----
    {
        int nroots = cnt[0];
        for (int task = tid; task < nroots * LL; task += BT) {
            int ni = task / LL, r = task - ni * LL;
            int n = order[ni];
            float acc = b_single[r];
            const float* feat = atom_d + n * LL;
            const float* wr = W_single + r * LL;
            #pragma unroll 8
            for (int l = 0; l < LL; ++l) acc = fmaf(wr[l], feat[l], acc);
            float v = fmaxf(acc, 0.f);
            out_d[n * LL + r] = v;
            if (n == NN - 1) last_buf[d * LL + r] = v;
        }
    }
    __syncthreads();

    const int maxlvl = s_maxlvl;

    // ---- per-thread prefetch state for my task (tid) of the NEXT tile ----
    int    pf_pi[PP];
    float  pf_po[PP][4];
    float4 pf_ft = {0.f, 0.f, 0.f, 0.f};
    int    pf_fresh = 0;
    bool   pf_valid = false;

#define DO_PREFETCH(NT0, NTC, FIN)                                              \
    {                                                                           \
        pf_valid = (tid < (NTC) * NG);                                          \
        pf_fresh = 0;                                                           \
        if (pf_valid) {                                                         \
            int ni_ = tid / NG, lg_ = tid - ni_ * NG;                           \
            int n_ = order[(NT0) + ni_];                                        \
            const int4* pp4_ = (const int4*)(pred_d + n_ * PP);                 \
            int4 pa_ = pp4_[0], pb_ = pp4_[1];                                  \
            pf_pi[0]=pa_.x; pf_pi[1]=pa_.y; pf_pi[2]=pa_.z; pf_pi[3]=pa_.w;     \
            pf_pi[4]=pb_.x; pf_pi[5]=pb_.y; pf_pi[6]=pb_.z; pf_pi[7]=pb_.w;     \
            pf_ft = *(const float4*)&atom_d[n_ * LL + lg_ * 4];                 \
            _Pragma("unroll")                                                   \
            for (int q_ = 0; q_ < PP; ++q_) {                                   \
                pf_po[q_][0]=0.f; pf_po[q_][1]=0.f; pf_po[q_][2]=0.f; pf_po[q_][3]=0.f; \
                if (pf_pi[q_] >= 0) {                                           \
                    if (lvl[pf_pi[q_]] <= (FIN)) {                              \
                        float4 t_ = *(const float4*)&out_d[pf_pi[q_] * LL + lg_ * 4]; \
                        pf_po[q_][0]=t_.x; pf_po[q_][1]=t_.y; pf_po[q_][2]=t_.z; pf_po[q_][3]=t_.w; \
                    } else pf_fresh |= (1 << q_);                               \
                }                                                               \
            }                                                                   \
        }                                                                       \
    }

    // softmax + split + LDS-store for one task, given po/pi/ft in registers
#define EMIT_X(NI, LG, PI, PO, FTV)                                             \
    {                                                                           \
        float4 aw_ = *(const float4*)&s_attn[(LG) * 4];                         \
        float awv_[4] = {aw_.x, aw_.y, aw_.z, aw_.w};                           \
        unsigned short oh_[8], ol_[8];                                          \
        _Pragma("unroll")                                                       \
        for (int f_ = 0; f_ < 4; ++f_) {                                        \
            float m_ = -1e30f;                                                  \
            _Pragma("unroll")                                                   \
            for (int q_ = 0; q_ < PP; ++q_)                                     \
                if ((PI)[q_] >= 0) m_ = fmaxf(m_, awv_[f_] * (PO)[q_][f_]);     \
            float den_ = 0.f, num_ = 0.f;                                       \
            _Pragma("unroll")                                                   \
            for (int q_ = 0; q_ < PP; ++q_) {                                   \
                if ((PI)[q_] >= 0) {                                            \
                    float e_ = __expf(fmaf(awv_[f_], (PO)[q_][f_], -m_));       \
                    den_ += e_;                                                 \
                    num_ = fmaf(e_, (PO)[q_][f_], num_);                        \
                }                                                               \
            }                                                                   \
            float agg_ = __fdividef(num_, den_);                                \
            split_bf16(agg_,      oh_[f_],     ol_[f_]);                        \
            split_bf16((FTV)[f_], oh_[4 + f_], ol_[4 + f_]);                    \
        }                                                                       \
        short4v h0_ = {(short)oh_[0], (short)oh_[1], (short)oh_[2], (short)oh_[3]}; \
        short4v l0_ = {(short)ol_[0], (short)ol_[1], (short)ol_[2], (short)ol_[3]}; \
        short4v h1_ = {(short)oh_[4], (short)oh_[5], (short)oh_[6], (short)oh_[7]}; \
        short4v l1_ = {(short)ol_[4], (short)ol_[5], (short)ol_[6], (short)ol_[7]}; \
        *(short4v*)&x_hi[NI][(LG)*4]      = h0_;                                \
        *(short4v*)&x_lo[NI][(LG)*4]      = l0_;                                \
        *(short4v*)&x_hi[NI][LL + (LG)*4] = h1_;                                \
        *(short4v*)&x_lo[NI][LL + (LG)*4] = l1_;                                \
    }

    // initial prefetch: first tile of level 1 (fin = 0; all preds are level 0)
    if (maxlvl >= 1) {
        int ns = cnt[0], ne = cnt[1];
        DO_PREFETCH(ns, min(TMAX, ne - ns), 0);
    }

    // ---- 4. main level loop ----
    for (int L = 1; L <= maxlvl; ++L) {
        const int s = cnt[L - 1], e = cnt[L];
        for (int t0 = s; t0 < e; t0 += TMAX) {
            const int tc = min(TMAX, e - t0);
            const int ntask = tc * NG;

            // ---------- phase A ----------
            // second-round task: load indices + issue gathers EARLY
            const int t2 = tid + BT;
            const bool has2 = t2 < ntask;
            int pi2[PP]; float po2[PP][4]; float4 ft2; int ni2 = 0, lg2 = 0;
            if (has2) {
                ni2 = t2 / NG; lg2 = t2 - ni2 * NG;
                int n2 = order[t0 + ni2];
                const int4* pp4 = (const int4*)(pred_d + n2 * PP);
                int4 pa = pp4[0], pb = pp4[1];
                pi2[0]=pa.x; pi2[1]=pa.y; pi2[2]=pa.z; pi2[3]=pa.w;
                pi2[4]=pb.x; pi2[5]=pb.y; pi2[6]=pb.z; pi2[7]=pb.w;
                ft2 = *(const float4*)&atom_d[n2 * LL + lg2 * 4];
                #pragma unroll
                for (int q = 0; q < PP; ++q) {
                    po2[q][0]=po2[q][1]=po2[q][2]=po2[q][3]=0.f;
                    if (pi2[q] >= 0) {
                        float4 t = *(const float4*)&out_d[pi2[q] * LL + lg2 * 4];
                        po2[q][0]=t.x; po2[q][1]=t.y; po2[q][2]=t.z; po2[q][3]=t.w;
                    }
                }
            }
            // task 1: prefetched; fresh-gather only lvl==L-1 preds
            if (pf_valid) {
                int ni = tid / NG, lg = tid - ni * NG;
                #pragma unroll
                for (int q = 0; q < PP; ++q) {
                    if (pf_fresh & (1 << q)) {
                        float4 t = *(const float4*)&out_d[pf_pi[q] * LL + lg * 4];
                        pf_po[q][0]=t.x; pf_po[q][1]=t.y; pf_po[q][2]=t.z; pf_po[q][3]=t.w;
                    }
                }
                float ftv[4] = {pf_ft.x, pf_ft.y, pf_ft.z, pf_ft.w};
                EMIT_X(ni, lg, pf_pi, pf_po, ftv);
            }
            if (has2) {
                float ftv[4] = {ft2.x, ft2.y, ft2.z, ft2.w};
                EMIT_X(ni2, lg2, pi2, po2, ftv);
            }
            // residual rounds (ntask > 1024; only for tc > 39)
            for (int task = tid + 2*BT; task < ntask; task += BT) {
                int ni = task / NG, lg = task - ni * NG;
                int n = order[t0 + ni];
                const int4* pp4 = (const int4*)(pred_d + n * PP);
                int4 pa = pp4[0], pb = pp4[1];
                int pi[PP] = {pa.x, pa.y, pa.z, pa.w, pb.x, pb.y, pb.z, pb.w};
                float po[PP][4];
                #pragma unroll
                for (int q = 0; q < PP; ++q) {
                    po[q][0]=po[q][1]=po[q][2]=po[q][3]=0.f;
                    if (pi[q] >= 0) {
                        float4 t = *(const float4*)&out_d[pi[q] * LL + lg * 4];
                        po[q][0]=t.x; po[q][1]=t.y; po[q][2]=t.z; po[q][3]=t.w;
                    }
                }
                float4 ft = *(const float4*)&atom_d[n * LL + lg * 4];
                float ftv[4] = {ft.x, ft.y, ft.z, ft.w};
                EMIT_X(ni, lg, pi, po, ftv);
            }
            __syncthreads();

            // ---------- phase B (+ prefetch of next tile) ----------
            // next tile coordinates (uniform): same level else next level
            {
                int nt0 = -1, ntc = 0;
                if (t0 + TMAX < e)           { nt0 = t0 + TMAX; ntc = min(TMAX, e - nt0); }
                else if (L + 1 <= maxlvl)    { nt0 = e;         ntc = min(TMAX, cnt[L + 1] - e); }
                if (ntc > 0) { DO_PREFETCH(nt0, ntc, L - 1); }
                else pf_valid = false;
            }

            // MFMA jobs: 3 independent accumulator chains per nt
            const int mts = (tc + 15) >> 4;
            const int njobs = mts * 4;
            for (int job = wid; job < njobs; job += 8) {
                const int mt = job >> 2;        // job&3 == p by construction
                const int row_a = mt*16 + (lane & 15);
                const int kg = (lane >> 4) * 8;
                f32x4 a0 = {0.f,0.f,0.f,0.f}, b0 = {0.f,0.f,0.f,0.f}, c0 = {0.f,0.f,0.f,0.f};
                f32x4 a1 = {0.f,0.f,0.f,0.f}, b1 = {0.f,0.f,0.f,0.f}, c1 = {0.f,0.f,0.f,0.f};
                #pragma unroll
                for (int kt = 0; kt < 7; ++kt) {
                    const int k0 = kt*32 + kg;
                    short8 ah = *(const short8*)&x_hi[row_a][k0];
                    short8 al = *(const short8*)&x_lo[row_a][k0];
                    a0 = MFMA(ah, wh[0][kt], a0);
                    b0 = MFMA(ah, wl[0][kt], b0);
                    c0 = MFMA(al, wh[0][kt], c0);
                    if (p < 3) {
                        a1 = MFMA(ah, wh[1][kt], a1);
                        b1 = MFMA(ah, wl[1][kt], b1);
                        c1 = MFMA(al, wh[1][kt], c1);
                    }
                }
                f32x4 acc0 = a0 + b0 + c0;
                f32x4 acc1 = a1 + b1 + c1;
                const int r0 = p*32 + (lane & 15);
                #pragma unroll
                for (int j = 0; j < 4; ++j) {
                    int ni = mt*16 + (lane >> 4)*4 + j;
                    if (ni < tc) {
                        int n = order[t0 + ni];
                        if (r0 < LL) {
                            float v = fmaxf(acc0[j] + s_bm[r0], 0.f);
                            out_d[n*LL + r0] = v;
                            if (n == NN - 1) last_buf[d*LL + r0] = v;
                        }
                        if (p < 3) {
                            const int r1 = r0 + 16;
                            float v = fmaxf(acc1[j] + s_bm[r1], 0.f);
                            out_d[n*LL + r1] = v;
                            if (n == NN - 1) last_buf[d*LL + r1] = v;
                        }
                    }
                }
            }
            __syncthreads();  // x reuse + out_d visibility for next tile
        }
    }
}

// Cross-DAG softmax pool + final classifier. Single block.
__global__ __launch_bounds__(256) void final_pool_kernel(
    const float* __restrict__ last_buf,  // [DN][LL]
    const float* __restrict__ dag_w,     // [LL]
    const float* __restrict__ W_final,   // [CLS][LL]
    const float* __restrict__ b_final,   // [CLS]
    float* __restrict__ out)             // [CLS]
{
    __shared__ float s_pooled[LL];
    const int tid = threadIdx.x;

    if (tid < LL) {
        float dw = dag_w[tid];
        float m = -1e30f;
        #pragma unroll 8
        for (int dd = 0; dd < DN; ++dd)
            m = fmaxf(m, dw * last_buf[dd * LL + tid]);
        float den = 0.f, num = 0.f;
        #pragma unroll 8
        for (int dd = 0; dd < DN; ++dd) {
            float v = last_buf[dd * LL + tid];
            float e = __expf(dw * v - m);
            den += e;
            num = fmaf(e, v, num);
        }
        s_pooled[tid] = num / den;
    }
    __syncthreads();

    for (int c = tid; c < CLS; c += 256) {
        float acc = b_final[c];
        const float* wr = W_final + c * LL;
        #pragma unroll 8
        for (int l = 0; l < LL; ++l) acc = fmaf(wr[l], s_pooled[l], acc);
        out[c] = acc;
    }
}

extern "C" void kernel_launch(void* const* d_in, const int* in_sizes, int n_in,
                              void* d_out, int out_size, void* d_ws, size_t ws_size,
                              hipStream_t stream) {
    const float* atom     = (const float*)d_in[0];
    const int*   pred     = (const int*)  d_in[1];
    const float* W_single = (const float*)d_in[2];
    const float* b_single = (const float*)d_in[3];
    const float* W_merge  = (const float*)d_in[4];
    const float* b_merge  = (const float*)d_in[5];
    const float* attn_w   = (const float*)d_in[6];
    const float* dag_w    = (const float*)d_in[7];
    const float* W_final  = (const float*)d_in[8];
    const float* b_final  = (const float*)d_in[9];
    float* out = (float*)d_out;

    float* out_all  = (float*)d_ws;                       // [DN][NN][LL]
    float* last_buf = out_all + (size_t)DN * NN * LL;     // [DN][LL]

    dag_level_kernel<<<DN, BT, 0, stream>>>(atom, pred, W_single, b_single,
                                            W_merge, b_merge, attn_w,
                                            out_all, last_buf);
    final_pool_kernel<<<1, 256, 0, stream>>>(last_buf, dag_w, W_final, b_final, out);
}

// Round 8
// 367.486 us; speedup vs baseline: 1.7444x; 1.7444x over previous
//
#include <hip/hip_runtime.h>

#define DN  256   // DAGs
#define NN  1024  // nodes per DAG
#define PP  8     // max predecessors
#define LL  104   // feature dim
#define CLS 500   // classes
#define BT  512   // threads per block (8 waves -> W frags fit unified RF)
#define TMAX 64   // node tile per level pass
#define KP  232   // padded K stride in bf16 elems (116 dwords % 32 = 20 -> 2-way max, free)
#define NG  26    // float4 feature groups (104/4)

typedef __attribute__((ext_vector_type(8))) short short8;
typedef __attribute__((ext_vector_type(4))) short short4v;
typedef __attribute__((ext_vector_type(4))) float f32x4;

#define MFMA(a, b, c) __builtin_amdgcn_mfma_f32_16x16x32_bf16((a), (b), (c), 0, 0, 0)

__device__ __forceinline__ void split_bf16(float x, unsigned short& h, unsigned short& l) {
    unsigned u = __float_as_uint(x);
    h = (unsigned short)(u >> 16);
    float hf = __uint_as_float(u & 0xFFFF0000u);
    l = (unsigned short)(__float_as_uint(x - hf) >> 16);
}

// One block per DAG, 8 waves. Level-scheduled; per-level matvec batch is a
// split-bf16 MFMA GEMM with W_merge fragments pinned in registers/AGPRs.
// Phase A: BRANCHLESS gathers (clamped index, unconditional loads, arithmetic
// masking) so all 8 predecessor loads issue back-to-back per task.
__global__ __launch_bounds__(BT, 2) void dag_level_kernel(
    const float* __restrict__ atom,      // [DN][NN][LL]
    const int*   __restrict__ pred,      // [DN][NN][PP]
    const float* __restrict__ W_single,  // [LL][LL]
    const float* __restrict__ b_single,  // [LL]
    const float* __restrict__ W_merge,   // [LL][2*LL]
    const float* __restrict__ b_merge,   // [LL]
    const float* __restrict__ attn_w,    // [LL]
    float* __restrict__ out_all,         // ws: [DN][NN][LL]
    float* __restrict__ last_buf)        // ws: [DN][LL]
{
    __shared__ __align__(16) unsigned short x_hi[TMAX][KP];  // 29.7 KB
    __shared__ __align__(16) unsigned short x_lo[TMAX][KP];  // 29.7 KB
    __shared__ int   lvl[NN];               // 4 KB
    __shared__ int   cnt[NN];               // 4 KB
    __shared__ unsigned short order[NN];    // 2 KB
    __shared__ __align__(16) float s_attn2[LL];   // attn_w * log2(e)
    __shared__ float s_bm[LL];
    __shared__ int   csum[64];
    __shared__ int   s_flag, s_maxlvl;

    const int d    = blockIdx.x;
    const int tid  = threadIdx.x;
    const int wid  = tid >> 6;
    const int lane = tid & 63;
    const int p    = wid & 3;    // owned nt-pair: nt = {2p, 2p+1}

    const float* atom_d = atom + (size_t)d * NN * LL;
    const int*   pred_d = pred + (size_t)d * NN * PP;
    float*       out_d  = out_all + (size_t)d * NN * LL;

    // ---- W_merge fragments -> registers (once). B-frag layout:
    // lane holds W[col = nt*16 + (lane&15)][k = kt*32 + (lane>>4)*8 + j].
    short8 wh[2][7], wl[2][7];
    #pragma unroll
    for (int h = 0; h < 2; ++h) {
        const int r = (2*p + h)*16 + (lane & 15);
        #pragma unroll
        for (int kt = 0; kt < 7; ++kt) {
            const int k0 = kt*32 + (lane >> 4)*8;
            short8 hh, lo8;
            #pragma unroll
            for (int j = 0; j < 8; ++j) {
                float v = (r < LL && (k0 + j) < 2*LL) ? W_merge[r*2*LL + k0 + j] : 0.f;
                unsigned short a, b;
                split_bf16(v, a, b);
                hh[j] = (short)a; lo8[j] = (short)b;
            }
            wh[h][kt] = hh; wl[h][kt] = lo8;
        }
    }

    // ---- init: zero x pad cols, stage attn/bias, init flags ----
    for (int idx = tid; idx < TMAX * (KP - 2*LL); idx += BT) {
        int rr = idx / (KP - 2*LL), cc = 2*LL + (idx - rr*(KP - 2*LL));
        x_hi[rr][cc] = 0; x_lo[rr][cc] = 0;
    }
    if (tid < LL) { s_attn2[tid] = attn_w[tid] * 1.44269504f; s_bm[tid] = b_merge[tid]; }
    if (tid == 0) { s_flag = 0; s_maxlvl = 0; }

    // ---- 1. level relaxation (2 nodes per thread, preds in registers) ----
    {
        int mypA[PP], mypB[PP];
        const int4* p4 = (const int4*)(pred_d + tid * PP);
        int4 a = p4[0], b = p4[1];
        mypA[0]=a.x; mypA[1]=a.y; mypA[2]=a.z; mypA[3]=a.w;
        mypA[4]=b.x; mypA[5]=b.y; mypA[6]=b.z; mypA[7]=b.w;
        const int4* q4 = (const int4*)(pred_d + (tid + BT) * PP);
        int4 c = q4[0], e = q4[1];
        mypB[0]=c.x; mypB[1]=c.y; mypB[2]=c.z; mypB[3]=c.w;
        mypB[4]=e.x; mypB[5]=e.y; mypB[6]=e.z; mypB[7]=e.w;
        lvl[tid] = 0; lvl[tid + BT] = 0;
        __syncthreads();
        for (int it = 1; it <= NN; ++it) {
            int mxA = -1, mxB = -1;
            #pragma unroll
            for (int q = 0; q < PP; ++q) {
                if (mypA[q] >= 0) mxA = max(mxA, lvl[mypA[q]]);
                if (mypB[q] >= 0) mxB = max(mxB, lvl[mypB[q]]);
            }
            bool ch = false;
            if (mxA + 1 != lvl[tid])      { lvl[tid]      = mxA + 1; ch = true; }
            if (mxB + 1 != lvl[tid + BT]) { lvl[tid + BT] = mxB + 1; ch = true; }
            if (ch) s_flag = it;
            __syncthreads();
            int f = s_flag;
            __syncthreads();
            if (f != it) break;
        }
        atomicMax(&s_maxlvl, max(lvl[tid], lvl[tid + BT]));
    }

    // ---- 2. counting sort by level ----
    cnt[tid] = 0; cnt[tid + BT] = 0;
    __syncthreads();
    atomicAdd(&cnt[lvl[tid]], 1);
    atomicAdd(&cnt[lvl[tid + BT]], 1);
    __syncthreads();
    if (tid < 64) { int s = 0; for (int i = 0; i < 16; ++i) s += cnt[tid*16 + i]; csum[tid] = s; }
    __syncthreads();
    if (tid == 0) { int run = 0; for (int t = 0; t < 64; ++t) { int c = csum[t]; csum[t] = run; run += c; } }
    __syncthreads();
    if (tid < 64) {
        int run = csum[tid];
        for (int i = 0; i < 16; ++i) { int c = cnt[tid*16 + i]; cnt[tid*16 + i] = run; run += c; }
    }
    __syncthreads();
    {
        int pos = atomicAdd(&cnt[lvl[tid]], 1);      order[pos] = (unsigned short)tid;
        pos     = atomicAdd(&cnt[lvl[tid + BT]], 1); order[pos] = (unsigned short)(tid + BT);
    }
    __syncthreads();
    // level L occupies [L==0 ? 0 : cnt[L-1], cnt[L])

    // ---- 3. level-0 (root) nodes via W_single straight from global ----
    {
        int nroots = cnt[0];
        for (int task = tid; task < nroots * LL; task += BT) {
            int ni = task / LL, r = task - ni * LL;
            int n = order[ni];
            float acc = b_single[r];
            const float* feat = atom_d + n * LL;
            const float* wr = W_single + r * LL;
            #pragma unroll 8
            for (int l = 0; l < LL; ++l) acc = fmaf(wr[l], feat[l], acc);
            float v = fmaxf(acc, 0.f);
            out_d[n * LL + r] = v;
            if (n == NN - 1) last_buf[d * LL + r] = v;
        }
    }
    __syncthreads();

    // ---- 4. main level loop ----
    const int maxlvl = s_maxlvl;
    for (int L = 1; L <= maxlvl; ++L) {
        const int s = cnt[L - 1], e = cnt[L];
        for (int t0 = s; t0 < e; t0 += TMAX) {
            const int tc = min(TMAX, e - t0);

            // phase A: branchless gather + softmax for 4 features per task
            const int ntask = tc * NG;
            for (int task = tid; task < ntask; task += BT) {
                int ni = task / NG;
                int lg = task - ni * NG;
                int n  = order[t0 + ni];
                const int4* pp4 = (const int4*)(pred_d + n * PP);
                int4 pa = pp4[0], pb = pp4[1];
                int pi[PP] = {pa.x, pa.y, pa.z, pa.w, pb.x, pb.y, pb.z, pb.w};
                // unconditional clamped loads: all 8 issue back-to-back
                float4 po4[PP];
                #pragma unroll
                for (int q = 0; q < PP; ++q) {
                    int idx = max(pi[q], 0);     // node 0 always valid/written
                    po4[q] = *(const float4*)&out_d[idx * LL + lg * 4];
                }
                float4 ft = *(const float4*)&atom_d[n * LL + lg * 4];
                float4 aw = *(const float4*)&s_attn2[lg * 4];
                float po[PP][4];
                #pragma unroll
                for (int q = 0; q < PP; ++q) {
                    po[q][0] = po4[q].x; po[q][1] = po4[q].y;
                    po[q][2] = po4[q].z; po[q][3] = po4[q].w;
                }
                float awv[4] = {aw.x, aw.y, aw.z, aw.w};
                float ftv[4] = {ft.x, ft.y, ft.z, ft.w};
                unsigned short oh[8], ol[8];
                #pragma unroll
                for (int f = 0; f < 4; ++f) {
                    float den = 0.f, num = 0.f;
                    #pragma unroll
                    for (int q = 0; q < PP; ++q) {
                        // softmax is shift-invariant; values bounded -> no max pass
                        float e2 = exp2f(awv[f] * po[q][f]);
                        e2 = (pi[q] >= 0) ? e2 : 0.f;    // arithmetic mask
                        den += e2;
                        num = fmaf(e2, po[q][f], num);
                    }
                    float agg = __fdividef(num, den);
                    split_bf16(agg,    oh[f],     ol[f]);
                    split_bf16(ftv[f], oh[4 + f], ol[4 + f]);
                }
                short4v h0 = {(short)oh[0], (short)oh[1], (short)oh[2], (short)oh[3]};
                short4v l0 = {(short)ol[0], (short)ol[1], (short)ol[2], (short)ol[3]};
                short4v h1 = {(short)oh[4], (short)oh[5], (short)oh[6], (short)oh[7]};
                short4v l1 = {(short)ol[4], (short)ol[5], (short)ol[6], (short)ol[7]};
                *(short4v*)&x_hi[ni][lg*4]      = h0;
                *(short4v*)&x_lo[ni][lg*4]      = l0;
                *(short4v*)&x_hi[ni][LL + lg*4] = h1;
                *(short4v*)&x_lo[ni][LL + lg*4] = l1;
            }
            __syncthreads();

            // phase B: C[tc x 104] = X * W^T; W frags pinned (job ntp == p)
            const int mts = (tc + 15) >> 4;
            const int njobs = mts * 4;
            for (int job = wid; job < njobs; job += 8) {
                const int mt = job >> 2;        // job&3 == p by construction
                const int row_a = mt*16 + (lane & 15);
                const int kg = (lane >> 4) * 8;
                f32x4 a0 = {0.f,0.f,0.f,0.f}, b0 = {0.f,0.f,0.f,0.f}, c0 = {0.f,0.f,0.f,0.f};
                f32x4 a1 = {0.f,0.f,0.f,0.f}, b1 = {0.f,0.f,0.f,0.f}, c1 = {0.f,0.f,0.f,0.f};
                #pragma unroll
                for (int kt = 0; kt < 7; ++kt) {
                    const int k0 = kt*32 + kg;
                    short8 ah = *(const short8*)&x_hi[row_a][k0];
                    short8 al = *(const short8*)&x_lo[row_a][k0];
                    a0 = MFMA(ah, wh[0][kt], a0);
                    b0 = MFMA(ah, wl[0][kt], b0);
                    c0 = MFMA(al, wh[0][kt], c0);
                    if (p < 3) {
                        a1 = MFMA(ah, wh[1][kt], a1);
                        b1 = MFMA(ah, wl[1][kt], b1);
                        c1 = MFMA(al, wh[1][kt], c1);
                    }
                }
                f32x4 acc0 = a0 + b0 + c0;
                f32x4 acc1 = a1 + b1 + c1;
                const int r0 = p*32 + (lane & 15);
                #pragma unroll
                for (int j = 0; j < 4; ++j) {
                    int ni = mt*16 + (lane >> 4)*4 + j;
                    if (ni < tc) {
                        int n = order[t0 + ni];
                        if (r0 < LL) {
                            float v = fmaxf(acc0[j] + s_bm[r0], 0.f);
                            out_d[n*LL + r0] = v;
                            if (n == NN - 1) last_buf[d*LL + r0] = v;
                        }
                        if (p < 3) {
                            const int r1 = r0 + 16;
                            float v = fmaxf(acc1[j] + s_bm[r1], 0.f);
                            out_d[n*LL + r1] = v;
                            if (n == NN - 1) last_buf[d*LL + r1] = v;
                        }
                    }
                }
            }
            __syncthreads();  // x reuse + out_d visibility for next tile
        }
    }
}

// Cross-DAG softmax pool + final classifier. Single block.
__global__ __launch_bounds__(256) void final_pool_kernel(
    const float* __restrict__ last_buf,  // [DN][LL]
    const float* __restrict__ dag_w,     // [LL]
    const float* __restrict__ W_final,   // [CLS][LL]
    const float* __restrict__ b_final,   // [CLS]
    float* __restrict__ out)             // [CLS]
{
    __shared__ float s_pooled[LL];
    const int tid = threadIdx.x;

    if (tid < LL) {
        float dw = dag_w[tid];
        float m = -1e30f;
        #pragma unroll 8
        for (int dd = 0; dd < DN; ++dd)
            m = fmaxf(m, dw * last_buf[dd * LL + tid]);
        float den = 0.f, num = 0.f;
        #pragma unroll 8
        for (int dd = 0; dd < DN; ++dd) {
            float v = last_buf[dd * LL + tid];
            float e = __expf(dw * v - m);
            den += e;
            num = fmaf(e, v, num);
        }
        s_pooled[tid] = num / den;
    }
    __syncthreads();

    for (int c = tid; c < CLS; c += 256) {
        float acc = b_final[c];
        const float* wr = W_final + c * LL;
        #pragma unroll 8
        for (int l = 0; l < LL; ++l) acc = fmaf(wr[l], s_pooled[l], acc);
        out[c] = acc;
    }
}

extern "C" void kernel_launch(void* const* d_in, const int* in_sizes, int n_in,
                              void* d_out, int out_size, void* d_ws, size_t ws_size,
                              hipStream_t stream) {
    const float* atom     = (const float*)d_in[0];
    const int*   pred     = (const int*)  d_in[1];
    const float* W_single = (const float*)d_in[2];
    const float* b_single = (const float*)d_in[3];
    const float* W_merge  = (const float*)d_in[4];
    const float* b_merge  = (const float*)d_in[5];
    const float* attn_w   = (const float*)d_in[6];
    const float* dag_w    = (const float*)d_in[7];
    const float* W_final  = (const float*)d_in[8];
    const float* b_final  = (const float*)d_in[9];
    float* out = (float*)d_out;

    float* out_all  = (float*)d_ws;                       // [DN][NN][LL]
    float* last_buf = out_all + (size_t)DN * NN * LL;     // [DN][LL]

    dag_level_kernel<<<DN, BT, 0, stream>>>(atom, pred, W_single, b_single,
                                            W_merge, b_merge, attn_w,
                                            out_all, last_buf);
    final_pool_kernel<<<1, 256, 0, stream>>>(last_buf, dag_w, W_final, b_final, out);
}